// Round 1
// baseline (110.528 us; speedup 1.0000x reference)
//
#include <hip/hip_runtime.h>

#define NB_CONV 256
#define NB_COPY 1536
#define NTHR 256

// d_out layout: y[4096][64] followed by cache_new[4096][4][64][64]
__global__ __launch_bounds__(256)
void fmc_fused(const float* __restrict__ inputs,
               const float* __restrict__ cache,
               const float* __restrict__ wk,
               const float* __restrict__ bias,
               const int* __restrict__ idxp,
               float* __restrict__ y_out,
               float* __restrict__ cache_out)
{
    const int idx = idxp[0];
    int iw = idx % 64;        if (iw < 0)  iw += 64;
    int iwi = (idx - 1) % 64; if (iwi < 0) iwi += 64;
    const bool upd = (idx - 1) >= 0;   // EXCLUSIVE=True
    const int tid = threadIdx.x;

    if (blockIdx.x < NB_CONV) {
        // ---------------- conv part: y[b][fo] for 16 batch rows ----------------
        __shared__ float Ws[64][68];   // [ci][fo], padded stride
        __shared__ float Xs[64][18];   // [ci][b],  padded stride (8B-aligned pairs)
        const int bbase = blockIdx.x * 16;
        const int fog = tid & 15;      // fo group: fo = 4*fog
        const int bp  = tid >> 4;      // compute threads: bp<8 -> b pair

        float acc[2][4];
        if (tid < 128) {
            const float4 bv = *(const float4*)(bias + (fog << 2));
            acc[0][0]=bv.x; acc[0][1]=bv.y; acc[0][2]=bv.z; acc[0][3]=bv.w;
            acc[1][0]=bv.x; acc[1][1]=bv.y; acc[1][2]=bv.z; acc[1][3]=bv.w;
        }

        for (int kh = 0; kh < 4; ++kh) {
            for (int kw = 0; kw < 7; ++kw) {
                if (kh == 3 && kw >= 3) break;          // autoregressive mask
                const int col = iw - 3 + kw;            // window col -> cache col
                int kind;                                // 0 zero, 1 inputs, 2 cache
                int hs = kh;
                if (col < 0 || col >= 64) kind = 0;
                else if (!upd) kind = 2;
                else if (iw != 0) kind = (kh == 3 && col == iwi) ? 1 : 2;   // case A
                else if (iwi != 0) {                                        // case B: shift(add)
                    if (kh == 3) kind = 0;
                    else if (kh == 2 && col == iwi) kind = 1;
                    else { kind = 2; hs = kh + 1; }
                } else {                                                     // case C: add(shift)
                    if (kh == 3) kind = (col == 0) ? 1 : 0;
                    else { kind = 2; hs = kh + 1; }
                }

                __syncthreads();   // protect LDS from previous tap's readers
                // stage W tap: [ci][fo] 64x64
                const float* wt = wk + (kh * 7 + kw) * 4096;
                #pragma unroll
                for (int i = 0; i < 4; ++i) {
                    const int f4 = tid + (i << 8);
                    const int ci = f4 >> 4;
                    const int fo = (f4 & 15) << 2;
                    const float4 v = *(const float4*)(wt + ci * 64 + fo);
                    *(float4*)&Ws[ci][fo] = v;
                }
                // stage X (transposed): Xs[ci][b]
                {
                    const int bl = tid >> 4;
                    const int c4 = (tid & 15) << 2;
                    float4 v = make_float4(0.f, 0.f, 0.f, 0.f);
                    if (kind == 1)
                        v = *(const float4*)(inputs + (bbase + bl) * 64 + c4);
                    else if (kind == 2)
                        v = *(const float4*)(cache + ((((bbase + bl) << 2) + hs) * 64 + col) * 64 + c4);
                    Xs[c4 + 0][bl] = v.x;
                    Xs[c4 + 1][bl] = v.y;
                    Xs[c4 + 2][bl] = v.z;
                    Xs[c4 + 3][bl] = v.w;
                }
                __syncthreads();

                if (tid < 128) {
                    #pragma unroll 16
                    for (int ci = 0; ci < 64; ++ci) {
                        const float4 w = *(const float4*)&Ws[ci][fog << 2];
                        const float2 x = *(const float2*)&Xs[ci][bp << 1];
                        acc[0][0] = fmaf(x.x, w.x, acc[0][0]);
                        acc[0][1] = fmaf(x.x, w.y, acc[0][1]);
                        acc[0][2] = fmaf(x.x, w.z, acc[0][2]);
                        acc[0][3] = fmaf(x.x, w.w, acc[0][3]);
                        acc[1][0] = fmaf(x.y, w.x, acc[1][0]);
                        acc[1][1] = fmaf(x.y, w.y, acc[1][1]);
                        acc[1][2] = fmaf(x.y, w.z, acc[1][2]);
                        acc[1][3] = fmaf(x.y, w.w, acc[1][3]);
                    }
                }
            }
        }
        if (tid < 128) {
            float* y0 = y_out + (bbase + (bp << 1)) * 64 + (fog << 2);
            *(float4*)y0        = make_float4(acc[0][0], acc[0][1], acc[0][2], acc[0][3]);
            *(float4*)(y0 + 64) = make_float4(acc[1][0], acc[1][1], acc[1][2], acc[1][3]);
        }
    } else {
        // ---------------- copy part: cache_new (float4 stream) ----------------
        const float4* __restrict__ c4 = (const float4*)cache;
        const float4* __restrict__ i4 = (const float4*)inputs;
        float4* __restrict__ o4 = (float4*)cache_out;
        const int t0 = (blockIdx.x - NB_CONV) * NTHR + tid;
        const int stride = NB_COPY * NTHR;
        const int total = 4096 * 4096;   // 16,777,216 float4
        if (!upd) {
            for (int i = t0; i < total; i += stride) o4[i] = c4[i];
        } else if (iw != 0) {            // case A: plain copy + column override
            const int target = 3 * 1024 + iwi * 16;
            for (int i = t0; i < total; i += stride) {
                const int r = i & 4095;
                const float4* src = c4 + i;
                if ((r & ~15) == target)                       // h==3 && w==iwi
                    src = i4 + ((i >> 12) << 4) + (r & 15);
                o4[i] = *src;
            }
        } else if (iwi != 0) {           // case B: shift rows up, insert at (2,iwi), zero row 3
            for (int i = t0; i < total; i += stride) {
                const int r = i & 4095;
                const int h = r >> 10;
                float4 v = make_float4(0.f, 0.f, 0.f, 0.f);
                if (h == 2 && ((r >> 4) & 63) == iwi) v = i4[((i >> 12) << 4) + (r & 15)];
                else if (h < 3) v = c4[i + 1024];
                o4[i] = v;
            }
        } else {                         // case C: shift rows up, row 3 = inputs at col 0 else 0
            for (int i = t0; i < total; i += stride) {
                const int r = i & 4095;
                const int h = r >> 10;
                float4 v = make_float4(0.f, 0.f, 0.f, 0.f);
                if (h == 3) { if (((r >> 4) & 63) == 0) v = i4[((i >> 12) << 4) + (r & 15)]; }
                else v = c4[i + 1024];
                o4[i] = v;
            }
        }
    }
}

extern "C" void kernel_launch(void* const* d_in, const int* in_sizes, int n_in,
                              void* d_out, int out_size, void* d_ws, size_t ws_size,
                              hipStream_t stream) {
    const float* inputs = (const float*)d_in[0];
    const float* cache  = (const float*)d_in[1];
    const float* wk     = (const float*)d_in[2];
    const float* bias   = (const float*)d_in[3];
    const int*   idxp   = (const int*)d_in[4];
    float* y_out = (float*)d_out;
    float* cache_out = (float*)d_out + 4096 * 64;
    fmc_fused<<<NB_CONV + NB_COPY, NTHR, 0, stream>>>(inputs, cache, wk, bias, idxp,
                                                      y_out, cache_out);
}